// Round 8
// baseline (627.077 us; speedup 1.0000x reference)
//
#include <hip/hip_runtime.h>
#include <hip/hip_bf16.h>
#include <cmath>

// B=4, N=1024, DIM=1024, H=16, DH=64, M=16, QK_SCALE=10
typedef __attribute__((ext_vector_type(8))) short short8;
typedef __attribute__((ext_vector_type(4))) float f32x4;

__device__ __forceinline__ unsigned short to_bf(float f) {
  __hip_bfloat16 h = __float2bfloat16(f);
  return __builtin_bit_cast(unsigned short, h);
}

// -------- fp32 -> bf16 elementwise ------------------------------------------
__global__ __launch_bounds__(256)
void cvt_bf16x4(const float* __restrict__ in, unsigned short* __restrict__ out, int n4)
{
  int i = blockIdx.x * 256 + threadIdx.x;
  if (i < n4) {
    float4 v = ((const float4*)in)[i];
    ushort4 o;
    o.x = to_bf(v.x); o.y = to_bf(v.y); o.z = to_bf(v.z); o.w = to_bf(v.w);
    ((ushort4*)out)[i] = o;
  }
}

// -------- W [1024 k][1024 n] fp32 -> WT [n][k] bf16 -------------------------
__global__ __launch_bounds__(256)
void transpose_to_bf(const float* __restrict__ W, unsigned short* __restrict__ WT)
{
  __shared__ float tile[64][65];
  const int n0 = blockIdx.x * 64, k0 = blockIdx.y * 64;
  const int t = threadIdx.x, c = t & 63, r4 = t >> 6;
#pragma unroll
  for (int q = 0; q < 16; ++q) {
    int r = (q << 2) + r4;
    tile[r][c] = W[(size_t)(k0 + r) * 1024 + n0 + c];
  }
  __syncthreads();
#pragma unroll
  for (int q = 0; q < 16; ++q) {
    int r = (q << 2) + r4;
    WT[(size_t)(n0 + r) * 1024 + k0 + c] = to_bf(tile[c][r]);
  }
}

// ---- bf16 MFMA GEMM, 128x128 tile, BK=32, stride-80 LDS (conflict-free) ----
// mode 0: fp32 C; mode 1: bf16 V^T into vallT[b][n][16+nn];
// mode 2: fp32 C = sigmoid(acc + bias2[n])
__global__ __launch_bounds__(256)
void gemm_bf128(const unsigned short* __restrict__ A, const unsigned short* __restrict__ BT,
                float* __restrict__ C, unsigned short* __restrict__ Vout,
                const float* __restrict__ bias2, int mode)
{
  __shared__ __align__(16) unsigned short Ab[128 * 40];
  __shared__ __align__(16) unsigned short Bb[128 * 40];
  const int t = threadIdx.x, lane = t & 63, w = t >> 6;
  const int m = lane & 15, quad = lane >> 4;
  const int wm = w & 1, wn = w >> 1;
  const int row0 = blockIdx.y << 7, col0 = blockIdx.x << 7;

  f32x4 acc[4][4];
#pragma unroll
  for (int mi = 0; mi < 4; ++mi)
#pragma unroll
    for (int ni = 0; ni < 4; ++ni) acc[mi][ni] = (f32x4){0.f, 0.f, 0.f, 0.f};

  for (int kk = 0; kk < 1024; kk += 32) {
#pragma unroll
    for (int q = 0; q < 2; ++q) {
      int c = t + (q << 8);
      int r = c >> 2, kp = c & 3;
      uint4 va = *(const uint4*)(A + (size_t)(row0 + r) * 1024 + kk + kp * 8);
      *(uint4*)((char*)Ab + r * 80 + kp * 16) = va;
      uint4 vb = *(const uint4*)(BT + (size_t)(col0 + r) * 1024 + kk + kp * 8);
      *(uint4*)((char*)Bb + r * 80 + kp * 16) = vb;
    }
    __syncthreads();
    short8 af[4], bf[4];
#pragma unroll
    for (int mi = 0; mi < 4; ++mi)
      af[mi] = *(const short8*)((char*)Ab + ((wm << 6) + (mi << 4) + m) * 80 + quad * 16);
#pragma unroll
    for (int ni = 0; ni < 4; ++ni)
      bf[ni] = *(const short8*)((char*)Bb + ((wn << 6) + (ni << 4) + m) * 80 + quad * 16);
#pragma unroll
    for (int mi = 0; mi < 4; ++mi)
#pragma unroll
      for (int ni = 0; ni < 4; ++ni)
        acc[mi][ni] = __builtin_amdgcn_mfma_f32_16x16x32_bf16(af[mi], bf[ni], acc[mi][ni], 0, 0, 0);
    __syncthreads();
  }
  // C/D layout: col = lane&15, row = quad*4 + reg
#pragma unroll
  for (int mi = 0; mi < 4; ++mi)
#pragma unroll
    for (int ni = 0; ni < 4; ++ni)
#pragma unroll
      for (int reg = 0; reg < 4; ++reg) {
        int mrow = row0 + (wm << 6) + (mi << 4) + (quad << 2) + reg;
        int ncol = col0 + (wn << 6) + (ni << 4) + m;
        float v = acc[mi][ni][reg];
        if (mode == 0) {
          C[((size_t)mrow << 10) + ncol] = v;
        } else if (mode == 2) {
          float s = v + bias2[ncol];
          C[((size_t)mrow << 10) + ncol] = 1.f / (1.f + __expf(-s));
        } else {
          int bb = mrow >> 10, nn = mrow & 1023;
          Vout[((size_t)((bb << 10) + ncol)) * 1056 + 16 + nn] = to_bf(v);
        }
      }
}

// ---- fused head-gate projection: hg = sigmoid(x @ W_hg + b_hg) -------------
// thread (row, h); grid 256 x 256thr covers 4096 rows x 16 h
__global__ __launch_bounds__(256)
void hgate_proj(const float* __restrict__ x, const float* __restrict__ W,
                const float* __restrict__ bias, float* __restrict__ hg)
{
  int G = blockIdx.x * 256 + threadIdx.x;
  int row = G >> 4, h = G & 15;
  const float4* x4 = (const float4*)(x + ((size_t)row << 10));
  float acc = 0.f;
#pragma unroll 4
  for (int k4 = 0; k4 < 256; ++k4) {
    float4 xv = x4[k4];
    int kb = k4 << 2;
    acc += xv.x * W[(kb + 0) * 16 + h] + xv.y * W[(kb + 1) * 16 + h]
         + xv.z * W[(kb + 2) * 16 + h] + xv.w * W[(kb + 3) * 16 + h];
  }
  float v = acc + bias[h];
  hg[(row << 4) + h] = 1.f / (1.f + __expf(-v));
}

// ------ q post: l2norm * scale * QK_SCALE + rope -> bf16 qb -----------------
__global__ __launch_bounds__(256)
void q_post_bf(const float* __restrict__ q_lin, const float* __restrict__ scale,
               const float* __restrict__ freqs, unsigned short* __restrict__ qb)
{
  int gid = blockIdx.x * 256 + threadIdx.x;
  int d = gid & 63;
  int row = gid >> 6;
  int h = row & 15;
  int n = (row >> 4) & 1023;
  float v = q_lin[gid];
  float ss = v * v;
#pragma unroll
  for (int off = 32; off; off >>= 1) ss += __shfl_xor(ss, off);
  v = v / fmaxf(sqrtf(ss), 1e-12f) * scale[(h << 6) + d];
  float f = freqs[(n << 6) + d];
  float other = __shfl_xor(v, 1);
  float rot = (d & 1) ? other : -other;
  qb[gid] = to_bf((v * cosf(f) + rot * sinf(f)) * 10.f);   // QK_SCALE folded
}

// ------ k post: l2norm*scale + rope, bf16 into kall (row stride 1056) -------
__global__ __launch_bounds__(256)
void k_post_bf(const float* __restrict__ k_lin, const float* __restrict__ scale,
               const float* __restrict__ freqs, unsigned short* __restrict__ kall)
{
  int gid = blockIdx.x * 256 + threadIdx.x;
  int d = gid & 63;
  int row = gid >> 6;
  int h = row & 15;
  int n = (row >> 4) & 1023;
  int b = row >> 14;
  float v = k_lin[gid];
  float ss = v * v;
#pragma unroll
  for (int off = 32; off; off >>= 1) ss += __shfl_xor(ss, off);
  v = v / fmaxf(sqrtf(ss), 1e-12f) * scale[(h << 6) + d];
  float f = freqs[(n << 6) + d];
  float other = __shfl_xor(v, 1);
  float rot = (d & 1) ? other : -other;
  float out = v * cosf(f) + rot * sinf(f);
  kall[(size_t)(b * 1056 + 16 + n) * 1024 + (h << 6) + d] = to_bf(out);
}

// ------ memory slots into kall rows 0..15 and vallT cols 0..15 --------------
__global__ __launch_bounds__(256)
void mem_build(const float* __restrict__ mem_k, const float* __restrict__ mem_v,
               const float* __restrict__ k_scale,
               unsigned short* __restrict__ kall, unsigned short* __restrict__ vallT)
{
  int gid = blockIdx.x * 256 + threadIdx.x;   // 16384 = H*M*64
  int d = gid & 63;
  int row = gid >> 6;            // h*M + mm
  int h = row >> 4, mm = row & 15;
  float v = mem_k[gid];
  float ss = v * v;
#pragma unroll
  for (int off = 32; off; off >>= 1) ss += __shfl_xor(ss, off);
  unsigned short kb = to_bf(v / fmaxf(sqrtf(ss), 1e-12f) * k_scale[(h << 6) + d]);
  unsigned short vb = to_bf(mem_v[gid]);
#pragma unroll
  for (int b = 0; b < 4; ++b) {
    kall[(size_t)(b * 1056 + mm) * 1024 + (h << 6) + d] = kb;
    vallT[(size_t)((b << 10) + (h << 6) + d) * 1056 + mm] = vb;
  }
}

// ================= two-pass MFMA attention, flat-balanced ===================
// Pass 1: L sums (additive, bounded logits -> exp(m-20)). Pass 2: normalize,
// W_post per (i,j) column, PV with v[g2]. QK processed per 16-j subtile so
// sS is 16*16*18 floats (18.4 KB) -> big occupancy win vs 32-j sS.

// ---- pass 1: denominators L[b][i][g] via atomicAdd -------------------------
__global__ __launch_bounds__(256, 4)
void attn_lsum(const unsigned short* __restrict__ qb, const unsigned short* __restrict__ kall,
               const float* __restrict__ W_pre, float* __restrict__ Lbuf)
{
  __shared__ float sS[16 * 16 * 18];            // [h][i][j 0..15], stride 18
  __shared__ float sWpre[256];

  const int t = threadIdx.x, lane = t & 63, w = t >> 6;
  const int m = lane & 15, quad = lane >> 4;
  sWpre[t] = W_pre[t];

  const int blk = blockIdx.x;                   // grid 1024
  const int u0 = (4352 * blk) >> 10, u1 = (4352 * (blk + 1)) >> 10;
  if (u0 == u1) return;

  int accu = 0, bi = 0;
  while (true) {
    int un = (((bi & 63) + 1) >> 1) + 1;
    if (accu + un > u0) break;
    accu += un; ++bi;
  }
  int b = bi >> 6, it = bi & 63, uoff = u0 - accu;

  short8 afr[4][2];
  float partL[16];
  bool fresh = true;

  for (int u = u0; u < u1; ++u) {
    const int i0 = it << 4;
    if (fresh) {
#pragma unroll
      for (int hh = 0; hh < 4; ++hh)
#pragma unroll
        for (int kk = 0; kk < 2; ++kk)
          afr[hh][kk] = *(const short8*)(qb + (((size_t)(b << 10) + i0 + m) << 10)
                                         + ((w << 2) + hh) * 64 + kk * 32 + quad * 8);
#pragma unroll
      for (int g = 0; g < 16; ++g) partL[g] = 0.f;
      fresh = false;
    }
    const int j0 = uoff << 5;
#pragma unroll
    for (int sub = 0; sub < 2; ++sub) {
      const int js = j0 + (sub << 4);
      // QK for this 16-j subtile
#pragma unroll
      for (int hh = 0; hh < 4; ++hh) {
        f32x4 s = (f32x4){0.f, 0.f, 0.f, 0.f};
#pragma unroll
        for (int kk = 0; kk < 2; ++kk) {
          short8 bfr = *(const short8*)(kall + ((size_t)(b * 1056 + js + m) << 10)
                                        + ((w << 2) + hh) * 64 + kk * 32 + quad * 8);
          s = __builtin_amdgcn_mfma_f32_16x16x32_bf16(afr[hh][kk], bfr, s, 0, 0, 0);
        }
#pragma unroll
        for (int reg = 0; reg < 4; ++reg)
          sS[(((w << 2) + hh) * 16 + (quad << 2) + reg) * 18 + m] = s[reg];
      }
      __syncthreads();
      // premix + exp accumulate
      {
        const int i_l = t >> 4, j_l = t & 15;
        const int ig = i0 + i_l;
        float ch[16];
#pragma unroll
        for (int h = 0; h < 16; ++h) ch[h] = sS[(h * 16 + i_l) * 18 + j_l];
        const bool ok = (js + j_l) <= ig + 16;
#pragma unroll
        for (int g = 0; g < 16; ++g) {
          float m0 = 0.f;
#pragma unroll
          for (int h = 0; h < 16; ++h) m0 += sWpre[(g << 4) + h] * ch[h];
          partL[g] += ok ? __expf(m0 - 20.f) : 0.f;
        }
      }
      __syncthreads();
    }
    ++uoff;
    if (uoff == ((it + 1) >> 1) + 1) {
#pragma unroll
      for (int g = 0; g < 16; ++g) {
        float v = partL[g];
        v += __shfl_xor(v, 1); v += __shfl_xor(v, 2);
        v += __shfl_xor(v, 4); v += __shfl_xor(v, 8);
        if (m == 0)
          atomicAdd(&Lbuf[(((size_t)(b << 10) + i0 + (w << 2) + quad) << 4) + g], v);
      }
      ++bi; b = bi >> 6; it = bi & 63; uoff = 0; fresh = true;
    }
  }
  if (!fresh) {
    const int i0 = it << 4;
#pragma unroll
    for (int g = 0; g < 16; ++g) {
      float v = partL[g];
      v += __shfl_xor(v, 1); v += __shfl_xor(v, 2);
      v += __shfl_xor(v, 4); v += __shfl_xor(v, 8);
      if (m == 0)
        atomicAdd(&Lbuf[(((size_t)(b << 10) + i0 + (w << 2) + quad) << 4) + g], v);
    }
  }
}

// ---- pass 2: recompute, normalize, W_post per column, PV with v[g2] --------
__global__ __launch_bounds__(256)
void attn_pv2(const unsigned short* __restrict__ qb, const unsigned short* __restrict__ kall,
              const unsigned short* __restrict__ vallT, const float* __restrict__ W_pre,
              const float* __restrict__ W_post, const float* __restrict__ Lbuf,
              float* __restrict__ Obuf)
{
  __shared__ float sS[16 * 16 * 18];            // [h][i][j 0..15], stride 18
  __shared__ unsigned short sE[16 * 16 * 40];   // bf16 p2 [g2][i][k 0..31 +8 pad]
  __shared__ float sWpre[256], sWpost[256], sIL[256];

  const int t = threadIdx.x, lane = t & 63, w = t >> 6;
  const int m = lane & 15, quad = lane >> 4;
  sWpre[t] = W_pre[t];
  sWpost[t] = W_post[t];

  const int blk = blockIdx.x;                   // grid 768
  const int u0 = (4352 * blk) / 768, u1 = (4352 * (blk + 1)) / 768;
  if (u0 == u1) return;

  int accu = 0, bi = 0;
  while (true) {
    int un = (((bi & 63) + 1) >> 1) + 1;
    if (accu + un > u0) break;
    accu += un; ++bi;
  }
  int b = bi >> 6, it = bi & 63, uoff = u0 - accu;

  short8 afr[4][2];
  f32x4 oacc[4][4];
  bool fresh = true;

  for (int u = u0; u < u1; ++u) {
    const int i0 = it << 4;
    if (fresh) {
#pragma unroll
      for (int hh = 0; hh < 4; ++hh)
#pragma unroll
        for (int kk = 0; kk < 2; ++kk)
          afr[hh][kk] = *(const short8*)(qb + (((size_t)(b << 10) + i0 + m) << 10)
                                         + ((w << 2) + hh) * 64 + kk * 32 + quad * 8);
#pragma unroll
      for (int a = 0; a < 4; ++a)
#pragma unroll
        for (int dt = 0; dt < 4; ++dt) oacc[a][dt] = (f32x4){0.f, 0.f, 0.f, 0.f};
      sIL[t] = 1.f / Lbuf[(((size_t)(b << 10) + i0 + (t >> 4)) << 4) + (t & 15)];
      fresh = false;
    }
    const int j0 = uoff << 5;
#pragma unroll
    for (int sub = 0; sub < 2; ++sub) {
      const int js = j0 + (sub << 4);
      // QK for this 16-j subtile
#pragma unroll
      for (int hh = 0; hh < 4; ++hh) {
        f32x4 s = (f32x4){0.f, 0.f, 0.f, 0.f};
#pragma unroll
        for (int kk = 0; kk < 2; ++kk) {
          short8 bfr = *(const short8*)(kall + ((size_t)(b * 1056 + js + m) << 10)
                                        + ((w << 2) + hh) * 64 + kk * 32 + quad * 8);
          s = __builtin_amdgcn_mfma_f32_16x16x32_bf16(afr[hh][kk], bfr, s, 0, 0, 0);
        }
#pragma unroll
        for (int reg = 0; reg < 4; ++reg)
          sS[(((w << 2) + hh) * 16 + (quad << 2) + reg) * 18 + m] = s[reg];
      }
      __syncthreads();   // also covers sIL write at fresh
      // premix + exp + normalize + W_post mix -> p2 (bf16, A-layout slot)
      {
        const int i_l = t >> 4, j_l = t & 15;
        const int ig = i0 + i_l;
        float ch[16];
#pragma unroll
        for (int h = 0; h < 16; ++h) ch[h] = sS[(h * 16 + i_l) * 18 + j_l];
        const bool ok = (js + j_l) <= ig + 16;
        float e[16];
#pragma unroll
        for (int g = 0; g < 16; ++g) {
          float m0 = 0.f;
#pragma unroll
          for (int h = 0; h < 16; ++h) m0 += sWpre[(g << 4) + h] * ch[h];
          e[g] = ok ? __expf(m0 - 20.f) * sIL[(i_l << 4) + g] : 0.f;
        }
#pragma unroll
        for (int g2 = 0; g2 < 16; ++g2) {
          float p = 0.f;
#pragma unroll
          for (int g = 0; g < 16; ++g) p += sWpost[(g2 << 4) + g] * e[g];
          sE[(g2 * 16 + i_l) * 40 + (sub << 4) + j_l] = to_bf(p);
        }
      }
      __syncthreads();
    }
    // PV over the 32-j unit: wave w owns g2 = 4w..4w+3, V indexed by g2
#pragma unroll
    for (int gl = 0; gl < 4; ++gl) {
      const int g2 = (w << 2) + gl;
      short8 a = *(const short8*)((const char*)sE + ((g2 * 16 + m) * 40 + quad * 8) * 2);
#pragma unroll
      for (int dt = 0; dt < 4; ++dt) {
        short8 bv = *(const short8*)(vallT + ((size_t)((b << 10) + g2 * 64 + dt * 16 + m)) * 1056
                                     + j0 + quad * 8);
        oacc[gl][dt] = __builtin_amdgcn_mfma_f32_16x16x32_bf16(a, bv, oacc[gl][dt], 0, 0, 0);
      }
    }
    ++uoff;
    if (uoff == ((it + 1) >> 1) + 1) {
#pragma unroll
      for (int gl = 0; gl < 4; ++gl) {
        int g2 = (w << 2) + gl;
#pragma unroll
        for (int dt = 0; dt < 4; ++dt)
#pragma unroll
          for (int reg = 0; reg < 4; ++reg)
            atomicAdd(&Obuf[(((size_t)(b << 10) + i0 + (quad << 2) + reg) << 10)
                            + g2 * 64 + dt * 16 + m], oacc[gl][dt][reg]);
      }
      ++bi; b = bi >> 6; it = bi & 63; uoff = 0; fresh = true;
    }
  }
  if (!fresh) {
    const int i0 = it << 4;
#pragma unroll
    for (int gl = 0; gl < 4; ++gl) {
      int g2 = (w << 2) + gl;
#pragma unroll
      for (int dt = 0; dt < 4; ++dt)
#pragma unroll
        for (int reg = 0; reg < 4; ++reg)
          atomicAdd(&Obuf[(((size_t)(b << 10) + i0 + (quad << 2) + reg) << 10)
                          + g2 * 64 + dt * 16 + m], oacc[gl][dt][reg]);
    }
  }
}

// ---- epilogue: aob = Obuf * hgate * vgate (bf16) ---------------------------
__global__ __launch_bounds__(256)
void gate_out(const float* __restrict__ Obuf, const float* __restrict__ hgate,
              const float* __restrict__ vgate, unsigned short* __restrict__ aob)
{
  int i4 = blockIdx.x * 256 + threadIdx.x;   // 1048576 float4 groups
  float4 o = ((const float4*)Obuf)[i4];
  int base = i4 << 2;
  int row = base >> 10, hd = base & 1023, h = hd >> 6;
  float hg = hgate[(row << 4) + h];
  float4 vg = ((const float4*)vgate)[i4];
  ushort4 r;
  r.x = to_bf(o.x * hg * vg.x);
  r.y = to_bf(o.y * hg * vg.y);
  r.z = to_bf(o.z * hg * vg.z);
  r.w = to_bf(o.w * hg * vg.w);
  ((ushort4*)aob)[i4] = r;
}

extern "C" void kernel_launch(void* const* d_in, const int* in_sizes, int n_in,
                              void* d_out, int out_size, void* d_ws, size_t ws_size,
                              hipStream_t stream)
{
  const float* x       = (const float*)d_in[0];
  const float* freqs   = (const float*)d_in[1];
  const float* Wq      = (const float*)d_in[2];
  const float* Wk      = (const float*)d_in[3];
  const float* Wv      = (const float*)d_in[4];
  const float* q_scale = (const float*)d_in[5];
  const float* k_scale = (const float*)d_in[6];
  const float* mem_k   = (const float*)d_in[7];
  const float* mem_v   = (const float*)d_in[8];
  const float* W_pre   = (const float*)d_in[9];
  const float* W_post  = (const float*)d_in[10];
  const float* W_hg    = (const float*)d_in[11];
  const float* b_hg    = (const float*)d_in[12];
  const float* W_vg    = (const float*)d_in[13];
  const float* b_vg    = (const float*)d_in[14];
  const float* Wo      = (const float*)d_in[15];
  float* out = (float*)d_out;
  float* ws  = (float*)d_ws;

  // workspace (float offsets), non-overlapping; total 19,660,800 f = 78.6 MiB
  float* q_lin = ws;                                        // [4096,1024]; dead -> aob
  unsigned short* aob = (unsigned short*)ws;
  float* k_lin = ws + 4194304;                              // [4096,1024]; dead -> Obuf
  float* Obuf  = k_lin;                                     // [4,1024,16,64] fp32
  float* vgbuf = ws + 8388608;                              // [4096,1024]
  float* hgbuf = ws + 12582912;                             // [4096,16]
  float* Lbuf  = ws + 12648448;                             // [4,1024,16]
  unsigned short* xb   = (unsigned short*)(ws + 12713984);  // [4096,1024] bf16 -> qb
  unsigned short* qb   = xb;                                // ends 14,811,136
  unsigned short* kall = (unsigned short*)(ws + 14811136);  // [4,1056,1024] bf16; ends 16,973,824
  unsigned short* vallT= (unsigned short*)(ws + 16973824);  // [4,1024,1056] bf16; ends 19,136,512
  unsigned short* wb   = (unsigned short*)(ws + 19136512);  // [1024,1024] bf16 (reused)

  dim3 blk(256);
  cvt_bf16x4<<<4096, blk, 0, stream>>>(x, xb, 1048576);
  // fused head-gate projection (fp32, reads original x)
  hgate_proj<<<256, blk, 0, stream>>>(x, W_hg, b_hg, hgbuf);
  // MFMA projections, 128x128 tiles (weight transpose buffer reused serially)
  transpose_to_bf<<<dim3(16, 16), blk, 0, stream>>>(Wq, wb);
  gemm_bf128<<<dim3(8, 32), blk, 0, stream>>>(xb, wb, q_lin, nullptr, nullptr, 0);
  transpose_to_bf<<<dim3(16, 16), blk, 0, stream>>>(Wk, wb);
  gemm_bf128<<<dim3(8, 32), blk, 0, stream>>>(xb, wb, k_lin, nullptr, nullptr, 0);
  transpose_to_bf<<<dim3(16, 16), blk, 0, stream>>>(Wv, wb);
  gemm_bf128<<<dim3(8, 32), blk, 0, stream>>>(xb, wb, nullptr, vallT, nullptr, 1);
  transpose_to_bf<<<dim3(16, 16), blk, 0, stream>>>(W_vg, wb);
  gemm_bf128<<<dim3(8, 32), blk, 0, stream>>>(xb, wb, vgbuf, nullptr, b_vg, 2);  // fused sigmoid
  // q/k/mem postprocessing (qb overwrites xb -- all xb readers done)
  q_post_bf<<<16384, blk, 0, stream>>>(q_lin, q_scale, freqs, qb);
  k_post_bf<<<16384, blk, 0, stream>>>(k_lin, k_scale, freqs, kall);
  mem_build<<<64, blk, 0, stream>>>(mem_k, mem_v, k_scale, kall, vallT);
  // zero accumulators (k_lin dead after k_post_bf -> Obuf alias)
  hipMemsetAsync(Lbuf, 0, 65536 * sizeof(float), stream);
  hipMemsetAsync(Obuf, 0, 4194304 * sizeof(float), stream);
  // two-pass attention + gate epilogue
  attn_lsum<<<1024, blk, 0, stream>>>(qb, kall, W_pre, Lbuf);
  attn_pv2<<<768, blk, 0, stream>>>(qb, kall, vallT, W_pre, W_post, Lbuf, Obuf);
  gate_out<<<4096, blk, 0, stream>>>(Obuf, hgbuf, vgbuf, aob);
  // output projection
  transpose_to_bf<<<dim3(16, 16), blk, 0, stream>>>(Wo, wb);
  gemm_bf128<<<dim3(8, 32), blk, 0, stream>>>(aob, wb, out, nullptr, nullptr, 0);
}

// Round 9
// 558.253 us; speedup vs baseline: 1.1233x; 1.1233x over previous
//
#include <hip/hip_runtime.h>
#include <hip/hip_bf16.h>
#include <cmath>

// B=4, N=1024, DIM=1024, H=16, DH=64, M=16, QK_SCALE=10
typedef __attribute__((ext_vector_type(8))) short short8;
typedef __attribute__((ext_vector_type(4))) float f32x4;

__device__ __forceinline__ unsigned short to_bf(float f) {
  __hip_bfloat16 h = __float2bfloat16(f);
  return __builtin_bit_cast(unsigned short, h);
}

// -------- fp32 -> bf16 elementwise ------------------------------------------
__global__ __launch_bounds__(256)
void cvt_bf16x4(const float* __restrict__ in, unsigned short* __restrict__ out, int n4)
{
  int i = blockIdx.x * 256 + threadIdx.x;
  if (i < n4) {
    float4 v = ((const float4*)in)[i];
    ushort4 o;
    o.x = to_bf(v.x); o.y = to_bf(v.y); o.z = to_bf(v.z); o.w = to_bf(v.w);
    ((ushort4*)out)[i] = o;
  }
}

// -------- W [1024 k][1024 n] fp32 -> WT [n][k] bf16 -------------------------
__global__ __launch_bounds__(256)
void transpose_to_bf(const float* __restrict__ W, unsigned short* __restrict__ WT)
{
  __shared__ float tile[64][65];
  const int n0 = blockIdx.x * 64, k0 = blockIdx.y * 64;
  const int t = threadIdx.x, c = t & 63, r4 = t >> 6;
#pragma unroll
  for (int q = 0; q < 16; ++q) {
    int r = (q << 2) + r4;
    tile[r][c] = W[(size_t)(k0 + r) * 1024 + n0 + c];
  }
  __syncthreads();
#pragma unroll
  for (int q = 0; q < 16; ++q) {
    int r = (q << 2) + r4;
    WT[(size_t)(n0 + r) * 1024 + k0 + c] = to_bf(tile[c][r]);
  }
}

// ---- bf16 MFMA GEMM, 128x128 tile, BK=32, stride-80 LDS, reg double-buffer -
// mode 0: fp32 C; mode 1: bf16 V^T into vallT[b][n][16+nn];
// mode 2: fp32 C = sigmoid(acc + bias2[n])
__global__ __launch_bounds__(256)
void gemm_bf128(const unsigned short* __restrict__ A, const unsigned short* __restrict__ BT,
                float* __restrict__ C, unsigned short* __restrict__ Vout,
                const float* __restrict__ bias2, int mode)
{
  __shared__ __align__(16) unsigned short Ab[128 * 40];
  __shared__ __align__(16) unsigned short Bb[128 * 40];
  const int t = threadIdx.x, lane = t & 63, w = t >> 6;
  const int m = lane & 15, quad = lane >> 4;
  const int wm = w & 1, wn = w >> 1;
  const int row0 = blockIdx.y << 7, col0 = blockIdx.x << 7;

  const int c0 = t,        r0 = c0 >> 2, kp0 = c0 & 3;
  const int c1 = t + 256,  r1 = c1 >> 2, kp1 = c1 & 3;

  f32x4 acc[4][4];
#pragma unroll
  for (int mi = 0; mi < 4; ++mi)
#pragma unroll
    for (int ni = 0; ni < 4; ++ni) acc[mi][ni] = (f32x4){0.f, 0.f, 0.f, 0.f};

  // prefetch k-tile 0
  uint4 pa0 = *(const uint4*)(A + (size_t)(row0 + r0) * 1024 + kp0 * 8);
  uint4 pa1 = *(const uint4*)(A + (size_t)(row0 + r1) * 1024 + kp1 * 8);
  uint4 pb0 = *(const uint4*)(BT + (size_t)(col0 + r0) * 1024 + kp0 * 8);
  uint4 pb1 = *(const uint4*)(BT + (size_t)(col0 + r1) * 1024 + kp1 * 8);

  for (int kk = 0; kk < 1024; kk += 32) {
    *(uint4*)((char*)Ab + r0 * 80 + kp0 * 16) = pa0;
    *(uint4*)((char*)Ab + r1 * 80 + kp1 * 16) = pa1;
    *(uint4*)((char*)Bb + r0 * 80 + kp0 * 16) = pb0;
    *(uint4*)((char*)Bb + r1 * 80 + kp1 * 16) = pb1;
    __syncthreads();
    if (kk + 32 < 1024) {      // next tile loads overlap the MFMA phase below
      pa0 = *(const uint4*)(A + (size_t)(row0 + r0) * 1024 + kk + 32 + kp0 * 8);
      pa1 = *(const uint4*)(A + (size_t)(row0 + r1) * 1024 + kk + 32 + kp1 * 8);
      pb0 = *(const uint4*)(BT + (size_t)(col0 + r0) * 1024 + kk + 32 + kp0 * 8);
      pb1 = *(const uint4*)(BT + (size_t)(col0 + r1) * 1024 + kk + 32 + kp1 * 8);
    }
    short8 af[4], bf[4];
#pragma unroll
    for (int mi = 0; mi < 4; ++mi)
      af[mi] = *(const short8*)((char*)Ab + ((wm << 6) + (mi << 4) + m) * 80 + quad * 16);
#pragma unroll
    for (int ni = 0; ni < 4; ++ni)
      bf[ni] = *(const short8*)((char*)Bb + ((wn << 6) + (ni << 4) + m) * 80 + quad * 16);
#pragma unroll
    for (int mi = 0; mi < 4; ++mi)
#pragma unroll
      for (int ni = 0; ni < 4; ++ni)
        acc[mi][ni] = __builtin_amdgcn_mfma_f32_16x16x32_bf16(af[mi], bf[ni], acc[mi][ni], 0, 0, 0);
    __syncthreads();
  }
  // C/D layout: col = lane&15, row = quad*4 + reg
#pragma unroll
  for (int mi = 0; mi < 4; ++mi)
#pragma unroll
    for (int ni = 0; ni < 4; ++ni)
#pragma unroll
      for (int reg = 0; reg < 4; ++reg) {
        int mrow = row0 + (wm << 6) + (mi << 4) + (quad << 2) + reg;
        int ncol = col0 + (wn << 6) + (ni << 4) + m;
        float v = acc[mi][ni][reg];
        if (mode == 0) {
          C[((size_t)mrow << 10) + ncol] = v;
        } else if (mode == 2) {
          float s = v + bias2[ncol];
          C[((size_t)mrow << 10) + ncol] = 1.f / (1.f + __expf(-s));
        } else {
          int bb = mrow >> 10, nn = mrow & 1023;
          Vout[((size_t)((bb << 10) + ncol)) * 1056 + 16 + nn] = to_bf(v);
        }
      }
}

// ---- fused head-gate projection: hg = sigmoid(x @ W_hg + b_hg) -------------
__global__ __launch_bounds__(256)
void hgate_proj(const float* __restrict__ x, const float* __restrict__ W,
                const float* __restrict__ bias, float* __restrict__ hg)
{
  int G = blockIdx.x * 256 + threadIdx.x;
  int row = G >> 4, h = G & 15;
  const float4* x4 = (const float4*)(x + ((size_t)row << 10));
  float acc = 0.f;
#pragma unroll 4
  for (int k4 = 0; k4 < 256; ++k4) {
    float4 xv = x4[k4];
    int kb = k4 << 2;
    acc += xv.x * W[(kb + 0) * 16 + h] + xv.y * W[(kb + 1) * 16 + h]
         + xv.z * W[(kb + 2) * 16 + h] + xv.w * W[(kb + 3) * 16 + h];
  }
  float v = acc + bias[h];
  hg[(row << 4) + h] = 1.f / (1.f + __expf(-v));
}

// ------ q post: l2norm * scale * QK_SCALE + rope -> bf16 qb -----------------
__global__ __launch_bounds__(256)
void q_post_bf(const float* __restrict__ q_lin, const float* __restrict__ scale,
               const float* __restrict__ freqs, unsigned short* __restrict__ qb)
{
  int gid = blockIdx.x * 256 + threadIdx.x;
  int d = gid & 63;
  int row = gid >> 6;
  int h = row & 15;
  int n = (row >> 4) & 1023;
  float v = q_lin[gid];
  float ss = v * v;
#pragma unroll
  for (int off = 32; off; off >>= 1) ss += __shfl_xor(ss, off);
  v = v / fmaxf(sqrtf(ss), 1e-12f) * scale[(h << 6) + d];
  float f = freqs[(n << 6) + d];
  float other = __shfl_xor(v, 1);
  float rot = (d & 1) ? other : -other;
  qb[gid] = to_bf((v * cosf(f) + rot * sinf(f)) * 10.f);   // QK_SCALE folded
}

// ------ k post: l2norm*scale + rope, bf16 into kall (row stride 1056) -------
__global__ __launch_bounds__(256)
void k_post_bf(const float* __restrict__ k_lin, const float* __restrict__ scale,
               const float* __restrict__ freqs, unsigned short* __restrict__ kall)
{
  int gid = blockIdx.x * 256 + threadIdx.x;
  int d = gid & 63;
  int row = gid >> 6;
  int h = row & 15;
  int n = (row >> 4) & 1023;
  int b = row >> 14;
  float v = k_lin[gid];
  float ss = v * v;
#pragma unroll
  for (int off = 32; off; off >>= 1) ss += __shfl_xor(ss, off);
  v = v / fmaxf(sqrtf(ss), 1e-12f) * scale[(h << 6) + d];
  float f = freqs[(n << 6) + d];
  float other = __shfl_xor(v, 1);
  float rot = (d & 1) ? other : -other;
  float out = v * cosf(f) + rot * sinf(f);
  kall[(size_t)(b * 1056 + 16 + n) * 1024 + (h << 6) + d] = to_bf(out);
}

// ------ memory slots into kall rows 0..15 and vallT cols 0..15 --------------
__global__ __launch_bounds__(256)
void mem_build(const float* __restrict__ mem_k, const float* __restrict__ mem_v,
               const float* __restrict__ k_scale,
               unsigned short* __restrict__ kall, unsigned short* __restrict__ vallT)
{
  int gid = blockIdx.x * 256 + threadIdx.x;   // 16384 = H*M*64
  int d = gid & 63;
  int row = gid >> 6;            // h*M + mm
  int h = row >> 4, mm = row & 15;
  float v = mem_k[gid];
  float ss = v * v;
#pragma unroll
  for (int off = 32; off; off >>= 1) ss += __shfl_xor(ss, off);
  unsigned short kb = to_bf(v / fmaxf(sqrtf(ss), 1e-12f) * k_scale[(h << 6) + d]);
  unsigned short vb = to_bf(mem_v[gid]);
#pragma unroll
  for (int b = 0; b < 4; ++b) {
    kall[(size_t)(b * 1056 + mm) * 1024 + (h << 6) + d] = kb;
    vallT[(size_t)((b << 10) + (h << 6) + d) * 1056 + mm] = vb;
  }
}

// ================= two-pass MFMA attention, flat-balanced ===================
// R7 structure (2 barriers/unit, 32-j premix, 2 cols/thread) + f32x4-packed
// weight broadcast tables (4x fewer LDS broadcast reads in premix/postmix).
// sWpre4[(h<<2)+p][e] = W_pre[(4p+e)*16+h]; m[4p+e] = sum_h(...).

// ---- pass 1: denominators L[b][i][g] via atomicAdd -------------------------
__global__ __launch_bounds__(256, 3)
void attn_lsum(const unsigned short* __restrict__ qb, const unsigned short* __restrict__ kall,
               const float* __restrict__ W_pre, float* __restrict__ Lbuf)
{
  __shared__ float sS[16 * 16 * 33];            // [h][i][j 0..31], stride 33
  __shared__ f32x4 sWpre4[64];

  const int t = threadIdx.x, lane = t & 63, w = t >> 6;
  const int m = lane & 15, quad = lane >> 4;
  if (t < 64) {
    int h = t >> 2, p4 = t & 3;
    sWpre4[t] = (f32x4){W_pre[(4 * p4 + 0) * 16 + h], W_pre[(4 * p4 + 1) * 16 + h],
                        W_pre[(4 * p4 + 2) * 16 + h], W_pre[(4 * p4 + 3) * 16 + h]};
  }

  const int blk = blockIdx.x;                   // grid 1024
  const int u0 = (4352 * blk) >> 10, u1 = (4352 * (blk + 1)) >> 10;
  if (u0 == u1) return;

  int accu = 0, bi = 0;
  while (true) {
    int un = (((bi & 63) + 1) >> 1) + 1;
    if (accu + un > u0) break;
    accu += un; ++bi;
  }
  int b = bi >> 6, it = bi & 63, uoff = u0 - accu;

  short8 afr[4][2];
  float partL[16];
  bool fresh = true;

  for (int u = u0; u < u1; ++u) {
    const int i0 = it << 4;
    if (fresh) {
#pragma unroll
      for (int hh = 0; hh < 4; ++hh)
#pragma unroll
        for (int kk = 0; kk < 2; ++kk)
          afr[hh][kk] = *(const short8*)(qb + (((size_t)(b << 10) + i0 + m) << 10)
                                         + ((w << 2) + hh) * 64 + kk * 32 + quad * 8);
#pragma unroll
      for (int g = 0; g < 16; ++g) partL[g] = 0.f;
      fresh = false;
    }
    const int j0 = uoff << 5;
    // ---- QK: both 16-j subtiles -> sS ----
#pragma unroll
    for (int sub = 0; sub < 2; ++sub) {
      const int js = j0 + (sub << 4);
#pragma unroll
      for (int hh = 0; hh < 4; ++hh) {
        f32x4 s = (f32x4){0.f, 0.f, 0.f, 0.f};
#pragma unroll
        for (int kk = 0; kk < 2; ++kk) {
          short8 bfr = *(const short8*)(kall + ((size_t)(b * 1056 + js + m) << 10)
                                        + ((w << 2) + hh) * 64 + kk * 32 + quad * 8);
          s = __builtin_amdgcn_mfma_f32_16x16x32_bf16(afr[hh][kk], bfr, s, 0, 0, 0);
        }
#pragma unroll
        for (int reg = 0; reg < 4; ++reg)
          sS[(((w << 2) + hh) * 16 + (quad << 2) + reg) * 33 + (sub << 4) + m] = s[reg];
      }
    }
    __syncthreads();
    // ---- packed premix + exp; 2 columns per thread ----
    {
      const int i_l = t >> 4, j_l = t & 15;
      const int ig = i0 + i_l;
      float ch0[16], ch1[16];
#pragma unroll
      for (int h = 0; h < 16; ++h) {
        ch0[h] = sS[(h * 16 + i_l) * 33 + j_l];
        ch1[h] = sS[(h * 16 + i_l) * 33 + 16 + j_l];
      }
      f32x4 a0[4], a1[4];
#pragma unroll
      for (int p = 0; p < 4; ++p) { a0[p] = (f32x4){0.f,0.f,0.f,0.f}; a1[p] = a0[p]; }
#pragma unroll
      for (int h = 0; h < 16; ++h) {
        float c0 = ch0[h], c1 = ch1[h];
#pragma unroll
        for (int p = 0; p < 4; ++p) {
          f32x4 wv = sWpre4[(h << 2) + p];
          a0[p] += wv * c0;
          a1[p] += wv * c1;
        }
      }
      const bool ok0 = (j0 + j_l) <= ig + 16;
      const bool ok1 = (j0 + 16 + j_l) <= ig + 16;
#pragma unroll
      for (int p = 0; p < 4; ++p)
#pragma unroll
        for (int e = 0; e < 4; ++e) {
          float v0 = ok0 ? __expf(a0[p][e] - 20.f) : 0.f;
          float v1 = ok1 ? __expf(a1[p][e] - 20.f) : 0.f;
          partL[(p << 2) + e] += v0 + v1;
        }
    }
    __syncthreads();
    ++uoff;
    if (uoff == ((it + 1) >> 1) + 1) {
#pragma unroll
      for (int g = 0; g < 16; ++g) {
        float v = partL[g];
        v += __shfl_xor(v, 1); v += __shfl_xor(v, 2);
        v += __shfl_xor(v, 4); v += __shfl_xor(v, 8);
        if (m == 0)
          atomicAdd(&Lbuf[(((size_t)(b << 10) + i0 + (w << 2) + quad) << 4) + g], v);
      }
      ++bi; b = bi >> 6; it = bi & 63; uoff = 0; fresh = true;
    }
  }
  if (!fresh) {
    const int i0 = it << 4;
#pragma unroll
    for (int g = 0; g < 16; ++g) {
      float v = partL[g];
      v += __shfl_xor(v, 1); v += __shfl_xor(v, 2);
      v += __shfl_xor(v, 4); v += __shfl_xor(v, 8);
      if (m == 0)
        atomicAdd(&Lbuf[(((size_t)(b << 10) + i0 + (w << 2) + quad) << 4) + g], v);
    }
  }
}

// ---- pass 2: recompute, normalize, W_post per column, PV with v[g2] --------
__global__ __launch_bounds__(256)
void attn_pv2(const unsigned short* __restrict__ qb, const unsigned short* __restrict__ kall,
              const unsigned short* __restrict__ vallT, const float* __restrict__ W_pre,
              const float* __restrict__ W_post, const float* __restrict__ Lbuf,
              float* __restrict__ Obuf)
{
  __shared__ float sS[16 * 16 * 33];            // [h][i][j 0..31]
  __shared__ unsigned short sE[16 * 16 * 40];   // bf16 p2 [g2][i][k 0..31 +8 pad]
  __shared__ f32x4 sWpre4[64], sWpost4[64];
  __shared__ float sIL[256];

  const int t = threadIdx.x, lane = t & 63, w = t >> 6;
  const int m = lane & 15, quad = lane >> 4;
  if (t < 64) {
    int h = t >> 2, p4 = t & 3;
    sWpre4[t]  = (f32x4){W_pre[(4 * p4 + 0) * 16 + h],  W_pre[(4 * p4 + 1) * 16 + h],
                         W_pre[(4 * p4 + 2) * 16 + h],  W_pre[(4 * p4 + 3) * 16 + h]};
    sWpost4[t] = (f32x4){W_post[(4 * p4 + 0) * 16 + h], W_post[(4 * p4 + 1) * 16 + h],
                         W_post[(4 * p4 + 2) * 16 + h], W_post[(4 * p4 + 3) * 16 + h]};
  }

  const int blk = blockIdx.x;                   // grid 512
  const int u0 = (4352 * blk) >> 9, u1 = (4352 * (blk + 1)) >> 9;
  if (u0 == u1) return;

  int accu = 0, bi = 0;
  while (true) {
    int un = (((bi & 63) + 1) >> 1) + 1;
    if (accu + un > u0) break;
    accu += un; ++bi;
  }
  int b = bi >> 6, it = bi & 63, uoff = u0 - accu;

  short8 afr[4][2];
  f32x4 oacc[4][4];
  bool fresh = true;

  for (int u = u0; u < u1; ++u) {
    const int i0 = it << 4;
    if (fresh) {
#pragma unroll
      for (int hh = 0; hh < 4; ++hh)
#pragma unroll
        for (int kk = 0; kk < 2; ++kk)
          afr[hh][kk] = *(const short8*)(qb + (((size_t)(b << 10) + i0 + m) << 10)
                                         + ((w << 2) + hh) * 64 + kk * 32 + quad * 8);
#pragma unroll
      for (int a = 0; a < 4; ++a)
#pragma unroll
        for (int dt = 0; dt < 4; ++dt) oacc[a][dt] = (f32x4){0.f, 0.f, 0.f, 0.f};
      sIL[t] = 1.f / Lbuf[(((size_t)(b << 10) + i0 + (t >> 4)) << 4) + (t & 15)];
      fresh = false;
    }
    const int j0 = uoff << 5;
    // ---- QK: both 16-j subtiles -> sS ----
#pragma unroll
    for (int sub = 0; sub < 2; ++sub) {
      const int js = j0 + (sub << 4);
#pragma unroll
      for (int hh = 0; hh < 4; ++hh) {
        f32x4 s = (f32x4){0.f, 0.f, 0.f, 0.f};
#pragma unroll
        for (int kk = 0; kk < 2; ++kk) {
          short8 bfr = *(const short8*)(kall + ((size_t)(b * 1056 + js + m) << 10)
                                        + ((w << 2) + hh) * 64 + kk * 32 + quad * 8);
          s = __builtin_amdgcn_mfma_f32_16x16x32_bf16(afr[hh][kk], bfr, s, 0, 0, 0);
        }
#pragma unroll
        for (int reg = 0; reg < 4; ++reg)
          sS[(((w << 2) + hh) * 16 + (quad << 2) + reg) * 33 + (sub << 4) + m] = s[reg];
      }
    }
    __syncthreads();   // also covers sIL write at fresh
    // ---- packed premix + exp + normalize + packed W_post -> p2 bf16 ----
    {
      const int i_l = t >> 4, j_l = t & 15;
      const int ig = i0 + i_l;
      float ch0[16], ch1[16];
#pragma unroll
      for (int h = 0; h < 16; ++h) {
        ch0[h] = sS[(h * 16 + i_l) * 33 + j_l];
        ch1[h] = sS[(h * 16 + i_l) * 33 + 16 + j_l];
      }
      f32x4 a0[4], a1[4];
#pragma unroll
      for (int p = 0; p < 4; ++p) { a0[p] = (f32x4){0.f,0.f,0.f,0.f}; a1[p] = a0[p]; }
#pragma unroll
      for (int h = 0; h < 16; ++h) {
        float c0 = ch0[h], c1 = ch1[h];
#pragma unroll
        for (int p = 0; p < 4; ++p) {
          f32x4 wv = sWpre4[(h << 2) + p];
          a0[p] += wv * c0;
          a1[p] += wv * c1;
        }
      }
      const bool ok0 = (j0 + j_l) <= ig + 16;
      const bool ok1 = (j0 + 16 + j_l) <= ig + 16;
      float e0[16], e1[16];
#pragma unroll
      for (int p = 0; p < 4; ++p)
#pragma unroll
        for (int e = 0; e < 4; ++e) {
          int g = (p << 2) + e;
          float il = sIL[(i_l << 4) + g];
          e0[g] = ok0 ? __expf(a0[p][e] - 20.f) * il : 0.f;
          e1[g] = ok1 ? __expf(a1[p][e] - 20.f) * il : 0.f;
        }
      f32x4 b0[4], b1[4];
#pragma unroll
      for (int p = 0; p < 4; ++p) { b0[p] = (f32x4){0.f,0.f,0.f,0.f}; b1[p] = b0[p]; }
#pragma unroll
      for (int g = 0; g < 16; ++g) {
        float c0 = e0[g], c1 = e1[g];
#pragma unroll
        for (int p = 0; p < 4; ++p) {
          f32x4 wv = sWpost4[(g << 2) + p];
          b0[p] += wv * c0;
          b1[p] += wv * c1;
        }
      }
#pragma unroll
      for (int p = 0; p < 4; ++p)
#pragma unroll
        for (int e = 0; e < 4; ++e) {
          int g2 = (p << 2) + e;
          sE[(g2 * 16 + i_l) * 40 + j_l] = to_bf(b0[p][e]);
          sE[(g2 * 16 + i_l) * 40 + 16 + j_l] = to_bf(b1[p][e]);
        }
    }
    __syncthreads();
    // ---- PV: wave w owns g2 = 4w..4w+3; V indexed by g2 (output head) ----
#pragma unroll
    for (int gl = 0; gl < 4; ++gl) {
      const int g2 = (w << 2) + gl;
      short8 a = *(const short8*)((const char*)sE + ((g2 * 16 + m) * 40 + quad * 8) * 2);
#pragma unroll
      for (int dt = 0; dt < 4; ++dt) {
        short8 bv = *(const short8*)(vallT + ((size_t)((b << 10) + g2 * 64 + dt * 16 + m)) * 1056
                                     + j0 + quad * 8);
        oacc[gl][dt] = __builtin_amdgcn_mfma_f32_16x16x32_bf16(a, bv, oacc[gl][dt], 0, 0, 0);
      }
    }
    ++uoff;
    if (uoff == ((it + 1) >> 1) + 1) {
#pragma unroll
      for (int gl = 0; gl < 4; ++gl) {
        int g2 = (w << 2) + gl;
#pragma unroll
        for (int dt = 0; dt < 4; ++dt)
#pragma unroll
          for (int reg = 0; reg < 4; ++reg)
            atomicAdd(&Obuf[(((size_t)(b << 10) + i0 + (quad << 2) + reg) << 10)
                            + g2 * 64 + dt * 16 + m], oacc[gl][dt][reg]);
      }
      ++bi; b = bi >> 6; it = bi & 63; uoff = 0; fresh = true;
    }
  }
  if (!fresh) {
    const int i0 = it << 4;
#pragma unroll
    for (int gl = 0; gl < 4; ++gl) {
      int g2 = (w << 2) + gl;
#pragma unroll
      for (int dt = 0; dt < 4; ++dt)
#pragma unroll
        for (int reg = 0; reg < 4; ++reg)
          atomicAdd(&Obuf[(((size_t)(b << 10) + i0 + (quad << 2) + reg) << 10)
                          + g2 * 64 + dt * 16 + m], oacc[gl][dt][reg]);
    }
  }
}

// ---- epilogue: aob = Obuf * hgate * vgate (bf16) ---------------------------
__global__ __launch_bounds__(256)
void gate_out(const float* __restrict__ Obuf, const float* __restrict__ hgate,
              const float* __restrict__ vgate, unsigned short* __restrict__ aob)
{
  int i4 = blockIdx.x * 256 + threadIdx.x;   // 1048576 float4 groups
  float4 o = ((const float4*)Obuf)[i4];
  int base = i4 << 2;
  int row = base >> 10, hd = base & 1023, h = hd >> 6;
  float hg = hgate[(row << 4) + h];
  float4 vg = ((const float4*)vgate)[i4];
  ushort4 r;
  r.x = to_bf(o.x * hg * vg.x);
  r.y = to_bf(o.y * hg * vg.y);
  r.z = to_bf(o.z * hg * vg.z);
  r.w = to_bf(o.w * hg * vg.w);
  ((ushort4*)aob)[i4] = r;
}

extern "C" void kernel_launch(void* const* d_in, const int* in_sizes, int n_in,
                              void* d_out, int out_size, void* d_ws, size_t ws_size,
                              hipStream_t stream)
{
  const float* x       = (const float*)d_in[0];
  const float* freqs   = (const float*)d_in[1];
  const float* Wq      = (const float*)d_in[2];
  const float* Wk      = (const float*)d_in[3];
  const float* Wv      = (const float*)d_in[4];
  const float* q_scale = (const float*)d_in[5];
  const float* k_scale = (const float*)d_in[6];
  const float* mem_k   = (const float*)d_in[7];
  const float* mem_v   = (const float*)d_in[8];
  const float* W_pre   = (const float*)d_in[9];
  const float* W_post  = (const float*)d_in[10];
  const float* W_hg    = (const float*)d_in[11];
  const float* b_hg    = (const float*)d_in[12];
  const float* W_vg    = (const float*)d_in[13];
  const float* b_vg    = (const float*)d_in[14];
  const float* Wo      = (const float*)d_in[15];
  float* out = (float*)d_out;
  float* ws  = (float*)d_ws;

  // workspace (float offsets), non-overlapping; total 19,660,800 f = 78.6 MiB
  float* q_lin = ws;                                        // [4096,1024]; dead -> aob+Lbuf
  unsigned short* aob = (unsigned short*)ws;                // [0 .. 2,097,152) floats-worth
  float* Lbuf  = ws + 4128768;                              // [4,1024,16] (q_lin tail, after aob)
  float* k_lin = ws + 4194304;                              // [4096,1024]; dead -> Obuf
  float* Obuf  = k_lin;                                     // [4,1024,16,64] fp32
  float* vgbuf = ws + 8388608;                              // [4096,1024]
  float* hgbuf = ws + 12582912;                             // [4096,16]
  unsigned short* xb   = (unsigned short*)(ws + 12713984);  // [4096,1024] bf16 -> qb
  unsigned short* qb   = xb;                                // ends 14,811,136
  unsigned short* kall = (unsigned short*)(ws + 14811136);  // [4,1056,1024] bf16; ends 16,973,824
  unsigned short* vallT= (unsigned short*)(ws + 16973824);  // [4,1024,1056] bf16; ends 19,136,512
  unsigned short* wb   = (unsigned short*)(ws + 19136512);  // [1024,1024] bf16 (reused)

  dim3 blk(256);
  cvt_bf16x4<<<4096, blk, 0, stream>>>(x, xb, 1048576);
  // fused head-gate projection (fp32, reads original x)
  hgate_proj<<<256, blk, 0, stream>>>(x, W_hg, b_hg, hgbuf);
  // MFMA projections, 128x128 tiles (weight transpose buffer reused serially)
  transpose_to_bf<<<dim3(16, 16), blk, 0, stream>>>(Wq, wb);
  gemm_bf128<<<dim3(8, 32), blk, 0, stream>>>(xb, wb, q_lin, nullptr, nullptr, 0);
  transpose_to_bf<<<dim3(16, 16), blk, 0, stream>>>(Wk, wb);
  gemm_bf128<<<dim3(8, 32), blk, 0, stream>>>(xb, wb, k_lin, nullptr, nullptr, 0);
  transpose_to_bf<<<dim3(16, 16), blk, 0, stream>>>(Wv, wb);
  gemm_bf128<<<dim3(8, 32), blk, 0, stream>>>(xb, wb, nullptr, vallT, nullptr, 1);
  transpose_to_bf<<<dim3(16, 16), blk, 0, stream>>>(W_vg, wb);
  gemm_bf128<<<dim3(8, 32), blk, 0, stream>>>(xb, wb, vgbuf, nullptr, b_vg, 2);  // fused sigmoid
  // q/k/mem postprocessing (qb overwrites xb -- all xb readers done)
  q_post_bf<<<16384, blk, 0, stream>>>(q_lin, q_scale, freqs, qb);
  k_post_bf<<<16384, blk, 0, stream>>>(k_lin, k_scale, freqs, kall);
  mem_build<<<64, blk, 0, stream>>>(mem_k, mem_v, k_scale, kall, vallT);
  // zero Lbuf+Obuf in ONE contiguous memset (q_lin/k_lin dead by now)
  hipMemsetAsync(Lbuf, 0, (65536 + 4194304) * sizeof(float), stream);
  // two-pass attention + gate epilogue
  attn_lsum<<<1024, blk, 0, stream>>>(qb, kall, W_pre, Lbuf);
  attn_pv2<<<512, blk, 0, stream>>>(qb, kall, vallT, W_pre, W_post, Lbuf, Obuf);
  gate_out<<<4096, blk, 0, stream>>>(Obuf, hgbuf, vgbuf, aob);
  // output projection
  transpose_to_bf<<<dim3(16, 16), blk, 0, stream>>>(Wo, wb);
  gemm_bf128<<<dim3(8, 32), blk, 0, stream>>>(aob, wb, out, nullptr, nullptr, 0);
}